// Round 5
// baseline (111.679 us; speedup 1.0000x reference)
//
#include <hip/hip_runtime.h>
#include <hip/hip_bf16.h>

// Deformable 3D conv: B=2, CIN=COUT=64, D=8,H=32,W=32, K=27, stride=1,pad=1,dil=1
// Round 5: barrier-free wave-owned pipelines. Each wave samples AND consumes its
// own 16-position tile (same-wave LDS, no __syncthreads). K split 9 ways across
// blockIdx.y (3 k/block, 2304 blocks, 3/CU). One barrier per block (staging).
// Gathers as dwordx4: 8 lanes x 16B = one 128B corner line. ushort corner idx.

#define BB    2
#define CINC  64
#define COUTC 64
#define DDEP  8
#define HGT   32
#define WID   32
#define KK    27
#define KGRP  9
#define KPB   3         // k's per block
#define PP    8192      // DOUT*HOUT*WOUT
#define TP    64        // output positions per workgroup
#define LDW   72        // padded LDS row stride (bf16 elems); 144B keeps b128 16B-aligned

typedef short s16x8 __attribute__((ext_vector_type(8)));
typedef float f32x4 __attribute__((ext_vector_type(4)));
typedef unsigned short u16x8 __attribute__((ext_vector_type(8)));

__device__ __forceinline__ unsigned short f2bf(float f) {
    unsigned u = __builtin_bit_cast(unsigned, f);
    u += 0x7FFFu + ((u >> 16) & 1u);   // RNE
    return (unsigned short)(u >> 16);
}

__device__ __forceinline__ unsigned pack2bf(float lo, float hi) {
    return (unsigned)f2bf(lo) | ((unsigned)f2bf(hi) << 16);
}

__device__ __forceinline__ float bfu_lo(unsigned v) {
    return __builtin_bit_cast(float, v << 16);
}
__device__ __forceinline__ float bfu_hi(unsigned v) {
    return __builtin_bit_cast(float, v & 0xFFFF0000u);
}

// Fused pre-kernel:
//  blocks [0,256): transpose+convert x[b][c][s] fp32 -> xt[b][s][c] bf16
//  blocks [256,688): weight (COUT,CIN,27) fp32 -> wt[(k*64+o)*64+c] bf16
__global__ void pre_kernel(const float* __restrict__ x, const float* __restrict__ w,
                           unsigned short* __restrict__ xt, unsigned short* __restrict__ wt) {
    __shared__ float sT[64][65];
    const int t    = threadIdx.x;
    const int lane = t & 63;
    const int wv   = t >> 6;
    const int half = lane >> 5;
    const int c2   = lane & 31;
    int blk = blockIdx.x;
    if (blk < 256) {
        int b  = blk >> 7;
        int s0 = (blk & 127) * 64;
        #pragma unroll
        for (int i = 0; i < 16; ++i) {
            int c = wv * 16 + i;
            sT[c][lane] = x[(size_t)(b * CINC + c) * PP + s0 + lane];
        }
        __syncthreads();
        #pragma unroll
        for (int i = 0; i < 8; ++i) {
            int s = wv * 16 + 2 * i + half;
            unsigned pk = pack2bf(sT[2 * c2][s], sT[2 * c2 + 1][s]);
            *(unsigned*)&xt[(size_t)(b * PP + s0 + s) * 64 + 2 * c2] = pk;
        }
    } else {
        int id = (blk - 256) * 256 + t;
        if (id < KK * COUTC * CINC) {
            int c = id & 63;
            int o = (id >> 6) & 63;
            int k = id >> 12;
            wt[id] = f2bf(w[(o * CINC + c) * KK + k]);
        }
    }
}

__device__ __forceinline__ void acc8(float* s, int4 v, float wg) {
    s[0] += wg * bfu_lo((unsigned)v.x); s[1] += wg * bfu_hi((unsigned)v.x);
    s[2] += wg * bfu_lo((unsigned)v.y); s[3] += wg * bfu_hi((unsigned)v.y);
    s[4] += wg * bfu_lo((unsigned)v.z); s[5] += wg * bfu_hi((unsigned)v.z);
    s[6] += wg * bfu_lo((unsigned)v.w); s[7] += wg * bfu_hi((unsigned)v.w);
}

__global__ __launch_bounds__(256, 3) void deform_kernel(
    const unsigned short* __restrict__ xt, const float* __restrict__ off,
    const unsigned short* __restrict__ wt, const float* __restrict__ bias,
    float* __restrict__ out)
{
    __shared__ unsigned short sW[KPB * COUTC * LDW] __attribute__((aligned(16))); // 3x [o][c]
    __shared__ unsigned short sS[TP * LDW]          __attribute__((aligned(16))); // [p][c], rows owned per wave
    __shared__ u16x8 sIdx[KPB][TP] __attribute__((aligned(16)));  // 8 corner dhw-indices
    __shared__ float sCf[KPB][TP][8] __attribute__((aligned(16)));// 8 corner weights

    const int t    = threadIdx.x;
    const int lane = t & 63;
    const int wv   = t >> 6;
    const int b    = blockIdx.x >> 7;
    const int p0   = (blockIdx.x & 127) * TP;
    const int kg   = blockIdx.y;           // 0..8

    const unsigned short* xb = xt + (size_t)b * PP * 64;

    f32x4 acc[4];
    #pragma unroll
    for (int f = 0; f < 4; ++f) acc[f] = (f32x4)0.0f;

    const int n0 = lane & 15;
    const int q  = lane >> 4;

    // ---- stage 3 weight tiles (coalesced 16B loads)
    {
        const unsigned short* wk = wt + (kg * KPB) * (COUTC * CINC);
        #pragma unroll
        for (int j = 0; j < 6; ++j) {
            int idx = j * 2048 + t * 8;
            int kl  = idx >> 12;
            int rem = idx & 4095;
            *(s16x8*)&sW[kl * (COUTC * LDW) + (rem >> 6) * LDW + (rem & 63)] =
                *(const s16x8*)(wk + idx);
        }
    }

    // ---- coords for 3 k's across 192 threads (validity fused into weights)
    if (t < KPB * TP) {
        int kl = t >> 6;
        int k  = kg * KPB + kl;
        int pl = t & 63;
        int pp = p0 + pl;
        int ow = pp & 31;
        int oh = (pp >> 5) & 31;
        int od = pp >> 10;
        int kd = k / 9;
        int kh = (k - kd * 9) / 3;
        int kw = k - kd * 9 - kh * 3;
        const float* ob = off + (size_t)(b * (3 * KK) + 3 * k) * PP + pp;
        float zd = (float)(od - 1 + kd) + ob[0];
        float zh = (float)(oh - 1 + kh) + ob[PP];
        float zw = (float)(ow - 1 + kw) + ob[2 * PP];

        float fdf = floorf(zd); int d0 = (int)fdf; float fd = zd - fdf;
        float fhf = floorf(zh); int h0 = (int)fhf; float fh = zh - fhf;
        float fwf = floorf(zw); int w0 = (int)fwf; float fw = zw - fwf;

        float Bd0 = (d0 >= 0     && d0 < DDEP)     ? 1.0f - fd : 0.0f;
        float Bd1 = (d0 + 1 >= 0 && d0 + 1 < DDEP) ? fd        : 0.0f;
        float Ch0 = (h0 >= 0     && h0 < HGT)      ? 1.0f - fh : 0.0f;
        float Ch1 = (h0 + 1 >= 0 && h0 + 1 < HGT)  ? fh        : 0.0f;
        float Aw0 = (w0 >= 0     && w0 < WID)      ? 1.0f - fw : 0.0f;
        float Aw1 = (w0 + 1 >= 0 && w0 + 1 < WID)  ? fw        : 0.0f;
        int dc0 = min(max(d0, 0), DDEP - 1);
        int dc1 = min(max(d0 + 1, 0), DDEP - 1);
        int hc0 = min(max(h0, 0), HGT - 1);
        int hc1 = min(max(h0 + 1, 0), HGT - 1);
        int wc0 = min(max(w0, 0), WID - 1);
        int wc1 = min(max(w0 + 1, 0), WID - 1);

        int dh0 = (dc0 * HGT + hc0) * WID;
        int dh1 = (dc0 * HGT + hc1) * WID;
        int dh2 = (dc1 * HGT + hc0) * WID;
        int dh3 = (dc1 * HGT + hc1) * WID;
        u16x8 iv;
        iv[0] = (unsigned short)(dh0 + wc0);
        iv[1] = (unsigned short)(dh1 + wc0);
        iv[2] = (unsigned short)(dh2 + wc0);
        iv[3] = (unsigned short)(dh3 + wc0);
        iv[4] = (unsigned short)(dh0 + wc1);
        iv[5] = (unsigned short)(dh1 + wc1);
        iv[6] = (unsigned short)(dh2 + wc1);
        iv[7] = (unsigned short)(dh3 + wc1);
        sIdx[kl][pl] = iv;
        float bc0 = Bd0 * Ch0, bc1 = Bd0 * Ch1, bc2 = Bd1 * Ch0, bc3 = Bd1 * Ch1;
        sCf[kl][pl][0] = bc0 * Aw0;
        sCf[kl][pl][1] = bc1 * Aw0;
        sCf[kl][pl][2] = bc2 * Aw0;
        sCf[kl][pl][3] = bc3 * Aw0;
        sCf[kl][pl][4] = bc0 * Aw1;
        sCf[kl][pl][5] = bc1 * Aw1;
        sCf[kl][pl][6] = bc2 * Aw1;
        sCf[kl][pl][7] = bc3 * Aw1;
    }
    __syncthreads();   // the ONLY barrier: sW/sIdx/sCf now visible to all waves

    // ---- wave-owned pipeline: sample own 16 positions, MFMA with own B-frags.
    // Same-wave LDS write->read: DS ops are in-order per wave, no barrier needed.
    const int coff = (lane & 7) * 8;   // 8 channels per lane
    #pragma unroll 1
    for (int kl = 0; kl < KPB; ++kl) {
        #pragma unroll
        for (int jp = 0; jp < 2; ++jp) {
            int prow = 16 * wv + 8 * jp + (lane >> 3);
            u16x8  iv = sIdx[kl][prow];
            float4 u0 = *(const float4*)&sCf[kl][prow][0];
            float4 u1 = *(const float4*)&sCf[kl][prow][4];
            const int4 v0 = *(const int4*)(xb + ((int)iv[0] << 6) + coff);
            const int4 v1 = *(const int4*)(xb + ((int)iv[1] << 6) + coff);
            const int4 v2 = *(const int4*)(xb + ((int)iv[2] << 6) + coff);
            const int4 v3 = *(const int4*)(xb + ((int)iv[3] << 6) + coff);
            const int4 v4 = *(const int4*)(xb + ((int)iv[4] << 6) + coff);
            const int4 v5 = *(const int4*)(xb + ((int)iv[5] << 6) + coff);
            const int4 v6 = *(const int4*)(xb + ((int)iv[6] << 6) + coff);
            const int4 v7 = *(const int4*)(xb + ((int)iv[7] << 6) + coff);
            float s[8] = {0, 0, 0, 0, 0, 0, 0, 0};
            acc8(s, v0, u0.x);
            acc8(s, v1, u0.y);
            acc8(s, v2, u0.z);
            acc8(s, v3, u0.w);
            acc8(s, v4, u1.x);
            acc8(s, v5, u1.y);
            acc8(s, v6, u1.z);
            acc8(s, v7, u1.w);
            int4 pk;
            pk.x = (int)pack2bf(s[0], s[1]);
            pk.y = (int)pack2bf(s[2], s[3]);
            pk.z = (int)pack2bf(s[4], s[5]);
            pk.w = (int)pack2bf(s[6], s[7]);
            *(int4*)&sS[prow * LDW + coff] = pk;
        }
        // MFMA: B = own 16 positions (rows 16wv+n0), A = 4 o-frags, Kdim=64
        {
            s16x8 b0 = *(const s16x8*)&sS[(16 * wv + n0) * LDW +      8 * q];
            s16x8 b1 = *(const s16x8*)&sS[(16 * wv + n0) * LDW + 32 + 8 * q];
            const unsigned short* sWk = &sW[kl * (COUTC * LDW)];
            #pragma unroll
            for (int f = 0; f < 4; ++f) {
                s16x8 a0 = *(const s16x8*)&sWk[(16 * f + n0) * LDW +      8 * q];
                s16x8 a1 = *(const s16x8*)&sWk[(16 * f + n0) * LDW + 32 + 8 * q];
                acc[f] = __builtin_amdgcn_mfma_f32_16x16x32_bf16(a0, b0, acc[f], 0, 0, 0);
                acc[f] = __builtin_amdgcn_mfma_f32_16x16x32_bf16(a1, b1, acc[f], 0, 0, 0);
            }
        }
    }

    // ---- epilogue: atomic partial accumulate; bias added by kg==0.
    // C/D layout: col=lane&15 -> p = p0+16wv+n0 ; row=4q+r -> o = 16f+4q+r
    const int pdst = p0 + 16 * wv + n0;
    #pragma unroll
    for (int f = 0; f < 4; ++f) {
        #pragma unroll
        for (int r = 0; r < 4; ++r) {
            int o = 16 * f + 4 * q + r;
            float add = acc[f][r] + ((kg == 0) ? bias[o] : 0.0f);
            unsafeAtomicAdd(&out[(size_t)(b * COUTC + o) * PP + pdst], add);
        }
    }
}

extern "C" void kernel_launch(void* const* d_in, const int* in_sizes, int n_in,
                              void* d_out, int out_size, void* d_ws, size_t ws_size,
                              hipStream_t stream) {
    const float* x    = (const float*)d_in[0];
    const float* off  = (const float*)d_in[1];
    const float* w    = (const float*)d_in[2];
    const float* bias = (const float*)d_in[3];
    float* out        = (float*)d_out;

    unsigned short* xt = (unsigned short*)d_ws;                       // 2*8192*64*2 = 2 MB
    unsigned short* wt = (unsigned short*)((char*)d_ws + (size_t)BB * PP * 64 * 2); // 221184 B

    (void)hipMemsetAsync(out, 0, (size_t)out_size * sizeof(float), stream);
    hipLaunchKernelGGL(pre_kernel, dim3(256 + (KK * COUTC * CINC + 255) / 256), dim3(256), 0,
                       stream, x, w, xt, wt);
    hipLaunchKernelGGL(deform_kernel, dim3(BB * (PP / TP), KGRP), dim3(256), 0, stream,
                       xt, off, wt, bias, out);
}